// Round 14
// baseline (739.431 us; speedup 1.0000x reference)
//
#include <hip/hip_runtime.h>
#include <hip/hip_bf16.h>

typedef long long TLONG;
typedef float  f32x4_t  __attribute__((ext_vector_type(4)));
typedef short  s16x8_t  __attribute__((ext_vector_type(8)));
typedef short  s16x4_t  __attribute__((ext_vector_type(4)));
typedef __bf16 bf16x8_t __attribute__((ext_vector_type(8)));

#define MDIM 32768
#define NDIM 1024
#define KDIM 1024
#define EPSV 1e-6f

#define BARRIER() asm volatile("s_barrier" ::: "memory")
#define SBAR() __builtin_amdgcn_sched_barrier(0)

__device__ __forceinline__ unsigned short f2bf_bits(float f) {
  __hip_bfloat16 h = __float2bfloat16(f);
  return __builtin_bit_cast(unsigned short, h);
}
__device__ __forceinline__ float bf2f(unsigned short u) {
  unsigned int x = ((unsigned int)u) << 16;
  return __builtin_bit_cast(float, x);
}
// async global->LDS, 16B per lane. LDS dest must be wave-uniform base + lane*16.
__device__ __forceinline__ void load_lds16(const void* g, void* l) {
  __builtin_amdgcn_global_load_lds((const __attribute__((address_space(1))) void*)g,
                                   (__attribute__((address_space(3))) void*)l, 16, 0, 0);
}

// nt LOADS (f32 read exactly once -> keep out of L3); REGULAR stores (outputs
// re-read by GEMMs -> want L3 residency). [R8: nt stores cost +26MB refetch]
__device__ __forceinline__ void conv8(const float* __restrict__ in,
                                      unsigned short* __restrict__ out, TLONG i) {
  f32x4_t a = __builtin_nontemporal_load(reinterpret_cast<const f32x4_t*>(in + i));
  f32x4_t b = __builtin_nontemporal_load(reinterpret_cast<const f32x4_t*>(in + i + 4));
  s16x8_t o;
  o[0] = (short)f2bf_bits(a[0]); o[1] = (short)f2bf_bits(a[1]);
  o[2] = (short)f2bf_bits(a[2]); o[3] = (short)f2bf_bits(a[3]);
  o[4] = (short)f2bf_bits(b[0]); o[5] = (short)f2bf_bits(b[1]);
  o[6] = (short)f2bf_bits(b[2]); o[7] = (short)f2bf_bits(b[3]);
  *reinterpret_cast<s16x8_t*>(out + i) = o;
}

// ---------------------------------------------------------------- converts
__global__ __launch_bounds__(256) void convert3_f32_bf16(
    const float* __restrict__ a, const float* __restrict__ b, const float* __restrict__ c,
    unsigned short* __restrict__ oa, unsigned short* __restrict__ ob,
    unsigned short* __restrict__ oc) {
  int blk = blockIdx.x;
  const float* in; unsigned short* out;
  if (blk < 2048)      { in = a; out = oa; }
  else if (blk < 4096) { in = b; out = ob; blk -= 2048; }
  else                 { in = c; out = oc; blk -= 4096; }
  const TLONG n = 33554432LL;
  TLONG i = ((TLONG)blk * 256 + threadIdx.x) * 8;
  const TLONG stride = 2048LL * 256 * 8;
  for (; i < n; i += stride) conv8(in, out, i);
}
__global__ __launch_bounds__(256) void convertW_f32_bf16(
    const float* __restrict__ a, const float* __restrict__ b, const float* __restrict__ c,
    const float* __restrict__ d, unsigned short* __restrict__ oa,
    unsigned short* __restrict__ ob, unsigned short* __restrict__ oc,
    unsigned short* __restrict__ od) {
  int blk = blockIdx.x;
  const float* in; unsigned short* out;
  if (blk < 512)       { in = a; out = oa; }
  else if (blk < 1024) { in = b; out = ob; blk -= 512; }
  else if (blk < 1536) { in = c; out = oc; blk -= 1024; }
  else                 { in = d; out = od; blk -= 1536; }
  TLONG i = ((TLONG)blk * 256 + threadIdx.x) * 8;
  conv8(in, out, i);
}
// kvT f32 (64*64*64) -> bf16, plain copy-convert (tiny, ~3us)
__global__ __launch_bounds__(256) void convert_kv(
    const float* __restrict__ in, unsigned short* __restrict__ out) {
  TLONG i = ((TLONG)blockIdx.x * 256 + threadIdx.x) * 8;  // 128 blocks x 2048
  f32x4_t a = *reinterpret_cast<const f32x4_t*>(in + i);
  f32x4_t b = *reinterpret_cast<const f32x4_t*>(in + i + 4);
  s16x8_t o;
  o[0] = (short)f2bf_bits(a[0]); o[1] = (short)f2bf_bits(a[1]);
  o[2] = (short)f2bf_bits(a[2]); o[3] = (short)f2bf_bits(a[3]);
  o[4] = (short)f2bf_bits(b[0]); o[5] = (short)f2bf_bits(b[1]);
  o[6] = (short)f2bf_bits(b[2]); o[7] = (short)f2bf_bits(b[3]);
  *reinterpret_cast<s16x8_t*>(out + i) = o;
}

// ---------------------------------------------------------------- GEMM 256x256 (R9 config verbatim)
template <int FMAP, int OUT>
__global__ __launch_bounds__(512, 2) void gemm256(
    const unsigned short* __restrict__ A, const unsigned short* __restrict__ W,
    const float* __restrict__ bias, void* __restrict__ Cout) {
  __shared__ short lds[65536];                    // [2 buf][A 16384 | B 16384] shorts
  const int bid = blockIdx.x;                     // 512 blocks
  const int swz = (bid & 7) * 64 + (bid >> 3);    // XCD-chunked (512%8==0)
  const int mt = swz >> 2;
  const int nt = swz & 3;

  const int tid = threadIdx.x;
  const int lane = tid & 63;
  const int w = tid >> 6;
  const int wr = w >> 2, wc = w & 3;
  const int l15 = lane & 15, lh = lane >> 4;

  const int arow0 = mt * 256, brow0 = nt * 256;

  auto stage_half = [&](const unsigned short* __restrict__ src, int ldsOff,
                        int grow, int k0) {
#pragma unroll
    for (int i = 0; i < 2; ++i) {
      const int c = i * 512 + tid;
      const int r = c >> 3, ps = c & 7;
      load_lds16(src + (grow + r) * KDIM + k0 + ((ps ^ (r & 7)) * 8),
                 &lds[ldsOff + c * 8]);
    }
  };

  f32x4_t acc[8][4];
#pragma unroll
  for (int m = 0; m < 8; ++m)
#pragma unroll
    for (int n = 0; n < 4; ++n) acc[m][n] = (f32x4_t)0.0f;

  s16x8_t Af[8][2], Bf[4][2];

  auto rdA = [&](int pb, int m, int ks) -> s16x8_t {
    const int row = wr * 128 + m * 16 + l15;
    return *reinterpret_cast<const s16x8_t*>(
        &lds[pb + row * 64 + (((ks * 4 + lh) ^ (row & 7)) * 8)]);
  };
  auto rdB = [&](int pb, int n, int ks) -> s16x8_t {
    const int row = wc * 64 + n * 16 + l15;
    return *reinterpret_cast<const s16x8_t*>(
        &lds[pb + 16384 + row * 64 + (((ks * 4 + lh) ^ (row & 7)) * 8)]);
  };
  auto quad = [&](int mb, int nl) {
    __builtin_amdgcn_s_setprio(1);
#pragma unroll
    for (int m = 0; m < 4; ++m)
#pragma unroll
      for (int n = 0; n < 2; ++n)
#pragma unroll
        for (int ks = 0; ks < 2; ++ks)
          acc[mb + m][nl + n] = __builtin_amdgcn_mfma_f32_16x16x32_bf16(
              __builtin_bit_cast(bf16x8_t, Af[mb + m][ks]),
              __builtin_bit_cast(bf16x8_t, Bf[nl + n][ks]),
              acc[mb + m][nl + n], 0, 0, 0);
    __builtin_amdgcn_s_setprio(0);
  };

  stage_half(A, 0,             arow0,       0);
  stage_half(A, 8192,          arow0 + 128, 0);
  stage_half(W, 16384,         brow0,       0);
  stage_half(W, 16384 + 8192,  brow0 + 128, 0);
  stage_half(A, 32768,         arow0,       64);
  stage_half(A, 32768 + 8192,  arow0 + 128, 64);
  asm volatile("s_waitcnt vmcnt(4)" ::: "memory");
  SBAR();
  BARRIER();

  for (int kt = 0; kt < 16; ++kt) {
    const int p = kt & 1;
    const int pb = p * 32768, qb = 32768 - pb;
    const int k1 = ((kt + 1) & 15) * 64;
    const int k2 = ((kt + 2) & 15) * 64;
#pragma unroll
    for (int m = 0; m < 4; ++m)
#pragma unroll
      for (int ks = 0; ks < 2; ++ks) Af[m][ks] = rdA(pb, m, ks);
#pragma unroll
    for (int n = 0; n < 2; ++n)
#pragma unroll
      for (int ks = 0; ks < 2; ++ks) Bf[n][ks] = rdB(pb, n, ks);
    SBAR();
#pragma unroll
    for (int m = 0; m < 4; ++m)
#pragma unroll
      for (int ks = 0; ks < 2; ++ks) Af[4 + m][ks] = rdA(pb, 4 + m, ks);
    SBAR();
#pragma unroll
    for (int n = 2; n < 4; ++n)
#pragma unroll
      for (int ks = 0; ks < 2; ++ks) Bf[n][ks] = rdB(pb, n, ks);
    SBAR();
    stage_half(W, qb + 16384, brow0, k1);
    BARRIER();
    asm volatile("s_waitcnt lgkmcnt(12)" ::: "memory");
    SBAR();
    quad(0, 0);
    BARRIER();
    stage_half(W, qb + 16384 + 8192, brow0 + 128, k1);
    BARRIER();
    asm volatile("s_waitcnt lgkmcnt(4)" ::: "memory");
    SBAR();
    quad(4, 0);
    BARRIER();
    stage_half(A, pb, arow0, k2);
    BARRIER();
    asm volatile("s_waitcnt lgkmcnt(0)" ::: "memory");
    SBAR();
    quad(0, 2);
    BARRIER();
    stage_half(A, pb + 8192, arow0 + 128, k2);
    BARRIER();
    quad(4, 2);
    asm volatile("s_waitcnt vmcnt(4)" ::: "memory");
    SBAR();
    BARRIER();
  }

#pragma unroll
  for (int n = 0; n < 4; ++n) {
    const int col = nt * 256 + wc * 64 + n * 16 + l15;
    const float bv = bias[col];
#pragma unroll
    for (int m = 0; m < 8; ++m) {
      const int row0 = mt * 256 + wr * 128 + m * 16 + lh * 4;
      if (OUT == 2) {
        const int b = row0 >> 13, tl = row0 & 8191;
        const int h = col >> 6, d = col & 63;
        s16x4_t o;
#pragma unroll
        for (int j = 0; j < 4; ++j) {
          float v = acc[m][n][j] + bv;
          if (FMAP) v = (v > 0.0f) ? (v + 1.0f) : __expf(v);
          o[j] = (short)f2bf_bits(v);
        }
        *reinterpret_cast<s16x4_t*>(
            reinterpret_cast<unsigned short*>(Cout) +
            (((b * 16 + h) * 64 + d) * 8192 + tl)) = o;
      } else {
#pragma unroll
        for (int j = 0; j < 4; ++j) {
          float v = acc[m][n][j] + bv;
          if (FMAP) v = (v > 0.0f) ? (v + 1.0f) : __expf(v);
          reinterpret_cast<unsigned short*>(Cout)[(row0 + j) * NDIM + col] = f2bf_bits(v);
        }
      }
    }
  }
}

// ---------------------------------------------------------------- fused final GEMM
// out[32768][1024] f32 = att @ Wo^T + bo, att computed on the fly:
// K-tile kt == head kt; A-tile[128][64] = (q_head @ kv) * rdenom, computed per
// tile by the block's 8 waves (16 rows each) and ds_written (swizzled) into the
// A double-buffer. Deletes attn_apply + 134MB att round-trip.
// Hazards: A/B buf-q writes happen after the single end-of-tile barrier that
// retired buf-q's readers (counted lgkm waits within the previous tile). No
// manual in-loop vmcnt: att operand loads are issued AFTER the Wo gload_lds;
// in-order vmem retirement + compiler's register-dep waits on att operands
// guarantee the B stages landed before the end barrier.
__global__ __launch_bounds__(512, 2) void gemm_out_fused(
    const unsigned short* __restrict__ qf,    // [32768][1024] bf16 (fmap'd q)
    const unsigned short* __restrict__ kvbf,  // [64 bh][64 e][64 d] bf16
    const float* __restrict__ ksum,           // [64 bh][64 d] f32
    const unsigned short* __restrict__ W,     // Wo bf16 [1024][1024]
    const float* __restrict__ bias, float* __restrict__ out) {
  __shared__ short lds[49152];   // A:[2][128][64] @0/8192 ; B:[2][256][64] @16384/32768
  const int bid = blockIdx.x;                    // 1024 blocks
  const int swz = (bid & 7) * 128 + (bid >> 3);  // XCD-chunked (1024%8==0)
  const int mt = swz >> 2;                       // 0..255 (nt inner -> q L2 reuse)
  const int nt = swz & 3;                        // 0..3

  const int tid = threadIdx.x;
  const int lane = tid & 63;
  const int w = tid >> 6;                        // 0..7
  const int wr = w >> 2, wc = w & 3;
  const int l15 = lane & 15, lh = lane >> 4;

  const int brow0 = nt * 256;
  const int row0A = mt * 128;
  const int bqbase = (mt >> 6) * 16;             // batch*16

  auto stage_halfB = [&](int ldsOff, int grow, int k0) {
#pragma unroll
    for (int i = 0; i < 2; ++i) {
      const int c = i * 512 + tid;
      const int r = c >> 3, ps = c & 7;
      load_lds16(W + (grow + r) * KDIM + k0 + ((ps ^ (r & 7)) * 8),
                 &lds[ldsOff + c * 8]);
    }
  };

  // att-tile compute for head h -> A buf at abase (wave rows [w*16, w*16+16))
  auto att_tile = [&](int h, int abase) {
    const int bh = bqbase + h;
    const TLONG grow = row0A + w * 16 + l15;
    const unsigned short* qrow = qf + grow * 1024 + h * 64;
    s16x8_t afr0 = *reinterpret_cast<const s16x8_t*>(qrow + lh * 8);
    s16x8_t afr1 = *reinterpret_cast<const s16x8_t*>(qrow + 32 + lh * 8);
    s16x8_t qa = *reinterpret_cast<const s16x8_t*>(qrow + lh * 16);
    s16x8_t qb = *reinterpret_cast<const s16x8_t*>(qrow + lh * 16 + 8);
    s16x8_t bf0[4], bf1[4];
#pragma unroll
    for (int n = 0; n < 4; ++n) {
      const unsigned short* kp = kvbf + ((bh * 64 + n * 16 + l15) * 64) + lh * 8;
      bf0[n] = *reinterpret_cast<const s16x8_t*>(kp);
      bf1[n] = *reinterpret_cast<const s16x8_t*>(kp + 32);
    }
    const float* ksp = ksum + bh * 64 + lh * 16;
    f32x4_t ks0 = *reinterpret_cast<const f32x4_t*>(ksp);
    f32x4_t ks1 = *reinterpret_cast<const f32x4_t*>(ksp + 4);
    f32x4_t ks2 = *reinterpret_cast<const f32x4_t*>(ksp + 8);
    f32x4_t ks3 = *reinterpret_cast<const f32x4_t*>(ksp + 12);
    float part = 0.f;
#pragma unroll
    for (int i = 0; i < 4; ++i) {
      part += bf2f((unsigned short)qa[i]) * ks0[i];
      part += bf2f((unsigned short)qa[4 + i]) * ks1[i];
      part += bf2f((unsigned short)qb[i]) * ks2[i];
      part += bf2f((unsigned short)qb[4 + i]) * ks3[i];
    }
    part += __shfl_xor(part, 16);
    part += __shfl_xor(part, 32);   // lane L holds denom of row L&15
    float rden[4];
#pragma unroll
    for (int j = 0; j < 4; ++j)
      rden[j] = 1.0f / (__shfl(part, lh * 4 + j) + EPSV);
    f32x4_t aacc[4];
#pragma unroll
    for (int n = 0; n < 4; ++n) aacc[n] = (f32x4_t)0.0f;
#pragma unroll
    for (int n = 0; n < 4; ++n) {
      aacc[n] = __builtin_amdgcn_mfma_f32_16x16x32_bf16(
          __builtin_bit_cast(bf16x8_t, afr0), __builtin_bit_cast(bf16x8_t, bf0[n]),
          aacc[n], 0, 0, 0);
      aacc[n] = __builtin_amdgcn_mfma_f32_16x16x32_bf16(
          __builtin_bit_cast(bf16x8_t, afr1), __builtin_bit_cast(bf16x8_t, bf1[n]),
          aacc[n], 0, 0, 0);
    }
    // C/D: col=n*16+l15, local row=lh*4+j; write swizzled b16 (2-way max aliasing)
#pragma unroll
    for (int n = 0; n < 4; ++n) {
      const int col = n * 16 + l15;
#pragma unroll
      for (int j = 0; j < 4; ++j) {
        const int lr = w * 16 + lh * 4 + j;
        lds[abase + lr * 64 + (((col >> 3) ^ (lr & 7)) * 8) + (col & 7)] =
            (short)f2bf_bits(aacc[n][j] * rden[j]);
      }
    }
  };

  f32x4_t acc[4][4];
#pragma unroll
  for (int m = 0; m < 4; ++m)
#pragma unroll
    for (int n = 0; n < 4; ++n) acc[m][n] = (f32x4_t)0.0f;

  s16x8_t Af[4][2], Bf[4][2];
  auto rdA = [&](int pbA, int m, int ks) -> s16x8_t {
    const int row = wr * 64 + m * 16 + l15;
    return *reinterpret_cast<const s16x8_t*>(
        &lds[pbA + row * 64 + (((ks * 4 + lh) ^ (row & 7)) * 8)]);
  };
  auto rdB = [&](int pbB, int n, int ks) -> s16x8_t {
    const int row = wc * 64 + n * 16 + l15;
    return *reinterpret_cast<const s16x8_t*>(
        &lds[pbB + row * 64 + (((ks * 4 + lh) ^ (row & 7)) * 8)]);
  };
  auto quad = [&](int nl) {
    __builtin_amdgcn_s_setprio(1);
#pragma unroll
    for (int m = 0; m < 4; ++m)
#pragma unroll
      for (int n = 0; n < 2; ++n)
#pragma unroll
        for (int ks = 0; ks < 2; ++ks)
          acc[m][nl + n] = __builtin_amdgcn_mfma_f32_16x16x32_bf16(
              __builtin_bit_cast(bf16x8_t, Af[m][ks]),
              __builtin_bit_cast(bf16x8_t, Bf[nl + n][ks]),
              acc[m][nl + n], 0, 0, 0);
    __builtin_amdgcn_s_setprio(0);
  };

  // prologue: Wo(0) -> B buf0 (gload); att(0) -> A buf0 (loads after stages)
  stage_halfB(16384, brow0, 0);
  stage_halfB(16384 + 8192, brow0 + 128, 0);
  SBAR();
  att_tile(0, 0);
  asm volatile("s_waitcnt lgkmcnt(0)" ::: "memory");   // att writes drained
  SBAR();
  BARRIER();

  for (int kt = 0; kt < 16; ++kt) {
    const int p = kt & 1;
    const int pbA = p * 8192, qbA = 8192 - pbA;
    const int pbB = 16384 + p * 16384, qbB = 16384 + (1 - p) * 16384;
    const int h1 = (kt + 1) & 15;            // wrapped tail: harmless recompute
    // main reads (buf p), pinned groups
#pragma unroll
    for (int m = 0; m < 4; ++m)
#pragma unroll
      for (int ks = 0; ks < 2; ++ks) Af[m][ks] = rdA(pbA, m, ks);
#pragma unroll
    for (int n = 0; n < 2; ++n)
#pragma unroll
      for (int ks = 0; ks < 2; ++ks) Bf[n][ks] = rdB(pbB, n, ks);
    SBAR();                                   // G1 (12 reads)
#pragma unroll
    for (int n = 2; n < 4; ++n)
#pragma unroll
      for (int ks = 0; ks < 2; ++ks) Bf[n][ks] = rdB(pbB, n, ks);
    SBAR();                                   // G2 (4 reads)
    // stage Wo(kt+1) FIRST (in-order proof), then att's global loads follow
    stage_halfB(qbB, brow0, h1 * 64);
    stage_halfB(qbB + 8192, brow0 + 128, h1 * 64);
    SBAR();
    asm volatile("s_waitcnt lgkmcnt(4)" ::: "memory");   // G1 done
    SBAR();
    quad(0);
    asm volatile("s_waitcnt lgkmcnt(0)" ::: "memory");   // G2 done
    SBAR();
    quad(2);
    // att(kt+1): loads (after Wo stages), 8 MFMA, denom, swizzled A writes
    att_tile(h1, qbA);
    asm volatile("s_waitcnt lgkmcnt(0)" ::: "memory");   // att ds_writes drained
    SBAR();
    BARRIER();                                // buf q ready; buf p readers done
  }

  // epilogue: f32 nt stores (final output, never re-read)
#pragma unroll
  for (int n = 0; n < 4; ++n) {
    const int col = nt * 256 + wc * 64 + n * 16 + l15;
    const float bv = bias[col];
#pragma unroll
    for (int m = 0; m < 4; ++m) {
      const int row0 = mt * 128 + wr * 64 + m * 16 + lh * 4;
#pragma unroll
      for (int j = 0; j < 4; ++j)
        __builtin_nontemporal_store(acc[m][n][j] + bv,
                                    &out[(TLONG)(row0 + j) * NDIM + col]);
    }
  }
}

// ---------------------------------------------------------------- kv + k_sum (MFMA, streaming)
__global__ __launch_bounds__(256) void kv_ksum_mfma(
    const unsigned short* __restrict__ kT, const unsigned short* __restrict__ vT,
    float* __restrict__ kvT, float* __restrict__ ksum) {
  const int bid = blockIdx.x;
  const int bh = bid >> 4, ch = bid & 15;
  const int tid = threadIdx.x;
  const int lane = tid & 63, w = tid >> 6;
  const int l15 = lane & 15, lh = lane >> 4;
  const int dblk = (w >> 1) * 32, eblk = (w & 1) * 32;

  f32x4_t acc[2][2];
#pragma unroll
  for (int m = 0; m < 2; ++m)
#pragma unroll
    for (int n = 0; n < 2; ++n) acc[m][n] = (f32x4_t)0.0f;
  float ks0 = 0.f, ks1 = 0.f;

  const int tbase = ch * 512 + lh * 8;
  const unsigned short* ka = kT + (bh * 64 + dblk + l15) * 8192 + tbase;
  const unsigned short* va = vT + (bh * 64 + eblk + l15) * 8192 + tbase;

  for (int t0 = 0; t0 < 512; t0 += 32) {
    s16x8_t ar[2], br[2];
#pragma unroll
    for (int m = 0; m < 2; ++m)
      ar[m] = *reinterpret_cast<const s16x8_t*>(ka + m * 16 * 8192 + t0);
#pragma unroll
    for (int n = 0; n < 2; ++n)
      br[n] = *reinterpret_cast<const s16x8_t*>(va + n * 16 * 8192 + t0);
#pragma unroll
    for (int m = 0; m < 2; ++m)
#pragma unroll
      for (int n = 0; n < 2; ++n)
        acc[m][n] = __builtin_amdgcn_mfma_f32_16x16x32_bf16(
            __builtin_bit_cast(bf16x8_t, ar[m]),
            __builtin_bit_cast(bf16x8_t, br[n]), acc[m][n], 0, 0, 0);
    if (eblk == 0) {
#pragma unroll
      for (int i = 0; i < 8; ++i) ks0 += bf2f((unsigned short)ar[0][i]);
#pragma unroll
      for (int i = 0; i < 8; ++i) ks1 += bf2f((unsigned short)ar[1][i]);
    }
  }

  if (eblk == 0) {
    ks0 += __shfl_xor(ks0, 16); ks0 += __shfl_xor(ks0, 32);
    ks1 += __shfl_xor(ks1, 16); ks1 += __shfl_xor(ks1, 32);
    if (lh == 0) {
      atomicAdd(&ksum[bh * 64 + dblk + l15], ks0);
      atomicAdd(&ksum[bh * 64 + dblk + 16 + l15], ks1);
    }
  }
#pragma unroll
  for (int n = 0; n < 2; ++n) {
    const int e = eblk + n * 16 + l15;
#pragma unroll
    for (int m = 0; m < 2; ++m) {
      const int d0 = dblk + m * 16 + lh * 4;
#pragma unroll
      for (int j = 0; j < 4; ++j)
        atomicAdd(&kvT[(bh * 64 + e) * 64 + d0 + j], acc[m][n][j]);
    }
  }
}

// ---------------------------------------------------------------- launch
extern "C" void kernel_launch(void* const* d_in, const int* in_sizes, int n_in,
                              void* d_out, int out_size, void* d_ws, size_t ws_size,
                              hipStream_t stream) {
  const float* query = (const float*)d_in[0];
  const float* key   = (const float*)d_in[1];
  const float* value = (const float*)d_in[2];
  const float* Wq = (const float*)d_in[3];
  const float* bq = (const float*)d_in[4];
  const float* Wk = (const float*)d_in[5];
  const float* bk = (const float*)d_in[6];
  const float* Wv = (const float*)d_in[7];
  const float* bv = (const float*)d_in[8];
  const float* Wo = (const float*)d_in[9];
  const float* bo = (const float*)d_in[10];
  float* out = (float*)d_out;

  if (ws_size < 277889024ULL) return;
  char* ws = (char*)d_ws;
  unsigned short* Vbf = (unsigned short*)(ws + 0);          // value bf16; kvbf after V-GEMM
  unsigned short* qf  = (unsigned short*)(ws + 67108864);
  unsigned short* kTf = (unsigned short*)(ws + 134217728);  // k transposed [b][h][d][t]
  unsigned short* vTf = (unsigned short*)(ws + 201326592);  // v transposed
  unsigned short* Wqb = (unsigned short*)(ws + 268435456);
  unsigned short* Wkb = Wqb + 1048576;
  unsigned short* Wvb = Wkb + 1048576;
  unsigned short* Wob = Wvb + 1048576;
  float* kvT  = (float*)(ws + 276824064);
  float* ksum = (float*)(ws + 277872640);
  unsigned short* kvbf = (unsigned short*)(ws + 0);         // overwrites Vbf (dead)

  unsigned short* Qbf = (unsigned short*)d_out;   // d_out doubles as bf16 scratch
  unsigned short* Kbf = Qbf + 33554432;

  hipMemsetAsync(kvT, 0, (size_t)(64 * 64 * 64 + 64 * 64) * sizeof(float), stream);

  convert3_f32_bf16<<<6144, 256, 0, stream>>>(query, key, value, Qbf, Kbf, Vbf);
  convertW_f32_bf16<<<2048, 256, 0, stream>>>(Wq, Wk, Wv, Wo, Wqb, Wkb, Wvb, Wob);

  gemm256<1, 0><<<512, 512, 0, stream>>>(Qbf, Wqb, bq, qf);   // q row-major
  gemm256<1, 2><<<512, 512, 0, stream>>>(Kbf, Wkb, bk, kTf);  // k transposed
  gemm256<0, 2><<<512, 512, 0, stream>>>(Vbf, Wvb, bv, vTf);  // v transposed

  kv_ksum_mfma<<<1024, 256, 0, stream>>>(kTf, vTf, kvT, ksum);
  convert_kv<<<128, 256, 0, stream>>>(kvT, kvbf);

  gemm_out_fused<<<1024, 512, 0, stream>>>(qf, kvbf, ksum, Wob, bo, out);
}

// Round 15
// 566.438 us; speedup vs baseline: 1.3054x; 1.3054x over previous
//
#include <hip/hip_runtime.h>
#include <hip/hip_bf16.h>

typedef long long TLONG;
typedef float  f32x4_t  __attribute__((ext_vector_type(4)));
typedef short  s16x8_t  __attribute__((ext_vector_type(8)));
typedef short  s16x4_t  __attribute__((ext_vector_type(4)));
typedef __bf16 bf16x8_t __attribute__((ext_vector_type(8)));

#define MDIM 32768
#define NDIM 1024
#define KDIM 1024
#define EPSV 1e-6f

#define BARRIER() asm volatile("s_barrier" ::: "memory")
#define SBAR() __builtin_amdgcn_sched_barrier(0)

__device__ __forceinline__ unsigned short f2bf_bits(float f) {
  __hip_bfloat16 h = __float2bfloat16(f);
  return __builtin_bit_cast(unsigned short, h);
}
__device__ __forceinline__ float bf2f(unsigned short u) {
  unsigned int x = ((unsigned int)u) << 16;
  return __builtin_bit_cast(float, x);
}
// async global->LDS, 16B per lane. LDS dest must be wave-uniform base + lane*16.
__device__ __forceinline__ void load_lds16(const void* g, void* l) {
  __builtin_amdgcn_global_load_lds((const __attribute__((address_space(1))) void*)g,
                                   (__attribute__((address_space(3))) void*)l, 16, 0, 0);
}

// nt LOADS (f32 read exactly once -> keep out of L3); REGULAR stores (outputs
// re-read by GEMMs -> want L3 residency). [R8: nt stores cost +26MB refetch]
__device__ __forceinline__ void conv8(const float* __restrict__ in,
                                      unsigned short* __restrict__ out, TLONG i) {
  f32x4_t a = __builtin_nontemporal_load(reinterpret_cast<const f32x4_t*>(in + i));
  f32x4_t b = __builtin_nontemporal_load(reinterpret_cast<const f32x4_t*>(in + i + 4));
  s16x8_t o;
  o[0] = (short)f2bf_bits(a[0]); o[1] = (short)f2bf_bits(a[1]);
  o[2] = (short)f2bf_bits(a[2]); o[3] = (short)f2bf_bits(a[3]);
  o[4] = (short)f2bf_bits(b[0]); o[5] = (short)f2bf_bits(b[1]);
  o[6] = (short)f2bf_bits(b[2]); o[7] = (short)f2bf_bits(b[3]);
  *reinterpret_cast<s16x8_t*>(out + i) = o;
}

// ---------------------------------------------------------------- merged convert
// blocks 0..6143: activations (2048 each, x8 grid-stride over 33.5M elems);
// blocks 6144..8191: weights (512 each, exactly 1M elems, single pass).
__global__ __launch_bounds__(256) void convert_all_f32_bf16(
    const float* __restrict__ q, const float* __restrict__ k, const float* __restrict__ v,
    const float* __restrict__ wq, const float* __restrict__ wk,
    const float* __restrict__ wv, const float* __restrict__ wo,
    unsigned short* __restrict__ oq, unsigned short* __restrict__ ok,
    unsigned short* __restrict__ ov, unsigned short* __restrict__ owq,
    unsigned short* __restrict__ owk, unsigned short* __restrict__ owv,
    unsigned short* __restrict__ owo) {
  int blk = blockIdx.x;
  if (blk < 6144) {
    const float* in; unsigned short* out;
    if (blk < 2048)      { in = q; out = oq; }
    else if (blk < 4096) { in = k; out = ok; blk -= 2048; }
    else                 { in = v; out = ov; blk -= 4096; }
    const TLONG n = 33554432LL;
    TLONG i = ((TLONG)blk * 256 + threadIdx.x) * 8;
    const TLONG stride = 2048LL * 256 * 8;
    for (; i < n; i += stride) conv8(in, out, i);
  } else {
    blk -= 6144;
    const float* in; unsigned short* out;
    if (blk < 512)       { in = wq; out = owq; }
    else if (blk < 1024) { in = wk; out = owk; blk -= 512; }
    else if (blk < 1536) { in = wv; out = owv; blk -= 1024; }
    else                 { in = wo; out = owo; blk -= 1536; }
    TLONG i = ((TLONG)blk * 256 + threadIdx.x) * 8;
    conv8(in, out, i);
  }
}

// ---------------------------------------------------------------- merged QKV GEMM (R9 ladder)
// 1536 blocks = 3 segments x 512. seg 0: q = fmap(query@Wq^T) row-major;
// seg 1: k = fmap(key@Wk^T) transposed; seg 2: v = value@Wv^T transposed.
// Per-segment pointer/mode selection is wave-uniform; hot loop identical to the
// measured-best R9 schedule (counted lgkm 12/4/0 ladder, one vmcnt(4)/tile).
// 512%8==0 -> per-segment XCD swizzle identical to the standalone version.
__global__ __launch_bounds__(512, 2) void gemm_qkv(
    const unsigned short* __restrict__ Aq, const unsigned short* __restrict__ Ak,
    const unsigned short* __restrict__ Av,
    const unsigned short* __restrict__ Wq, const unsigned short* __restrict__ Wk,
    const unsigned short* __restrict__ Wv,
    const float* __restrict__ bq, const float* __restrict__ bk,
    const float* __restrict__ bv,
    unsigned short* __restrict__ Cq, unsigned short* __restrict__ Ck,
    unsigned short* __restrict__ Cv) {
  __shared__ short lds[65536];                    // [2 buf][A 16384 | B 16384] shorts
  const int seg = blockIdx.x >> 9;                // 0,1,2
  const int local = blockIdx.x & 511;
  const unsigned short* A;
  const unsigned short* W;
  const float* bias;
  unsigned short* Cout;
  int fmap, outMode;
  if (seg == 0)      { A = Aq; W = Wq; bias = bq; Cout = Cq; fmap = 1; outMode = 0; }
  else if (seg == 1) { A = Ak; W = Wk; bias = bk; Cout = Ck; fmap = 1; outMode = 2; }
  else               { A = Av; W = Wv; bias = bv; Cout = Cv; fmap = 0; outMode = 2; }

  const int swz = (local & 7) * 64 + (local >> 3);  // XCD-chunked
  const int mt = swz >> 2;
  const int nt = swz & 3;

  const int tid = threadIdx.x;
  const int lane = tid & 63;
  const int w = tid >> 6;
  const int wr = w >> 2, wc = w & 3;
  const int l15 = lane & 15, lh = lane >> 4;

  const int arow0 = mt * 256, brow0 = nt * 256;

  auto stage_half = [&](const unsigned short* __restrict__ src, int ldsOff,
                        int grow, int k0) {
#pragma unroll
    for (int i = 0; i < 2; ++i) {
      const int c = i * 512 + tid;
      const int r = c >> 3, ps = c & 7;
      load_lds16(src + (grow + r) * KDIM + k0 + ((ps ^ (r & 7)) * 8),
                 &lds[ldsOff + c * 8]);
    }
  };

  f32x4_t acc[8][4];
#pragma unroll
  for (int m = 0; m < 8; ++m)
#pragma unroll
    for (int n = 0; n < 4; ++n) acc[m][n] = (f32x4_t)0.0f;

  s16x8_t Af[8][2], Bf[4][2];

  auto rdA = [&](int pb, int m, int ks) -> s16x8_t {
    const int row = wr * 128 + m * 16 + l15;
    return *reinterpret_cast<const s16x8_t*>(
        &lds[pb + row * 64 + (((ks * 4 + lh) ^ (row & 7)) * 8)]);
  };
  auto rdB = [&](int pb, int n, int ks) -> s16x8_t {
    const int row = wc * 64 + n * 16 + l15;
    return *reinterpret_cast<const s16x8_t*>(
        &lds[pb + 16384 + row * 64 + (((ks * 4 + lh) ^ (row & 7)) * 8)]);
  };
  auto quad = [&](int mb, int nl) {
    __builtin_amdgcn_s_setprio(1);
#pragma unroll
    for (int m = 0; m < 4; ++m)
#pragma unroll
      for (int n = 0; n < 2; ++n)
#pragma unroll
        for (int ks = 0; ks < 2; ++ks)
          acc[mb + m][nl + n] = __builtin_amdgcn_mfma_f32_16x16x32_bf16(
              __builtin_bit_cast(bf16x8_t, Af[mb + m][ks]),
              __builtin_bit_cast(bf16x8_t, Bf[nl + n][ks]),
              acc[mb + m][nl + n], 0, 0, 0);
    __builtin_amdgcn_s_setprio(0);
  };

  // prologue: kt0 all 4 halves -> buf0; kt1 A-halves -> buf1
  stage_half(A, 0,             arow0,       0);
  stage_half(A, 8192,          arow0 + 128, 0);
  stage_half(W, 16384,         brow0,       0);
  stage_half(W, 16384 + 8192,  brow0 + 128, 0);
  stage_half(A, 32768,         arow0,       64);
  stage_half(A, 32768 + 8192,  arow0 + 128, 64);
  asm volatile("s_waitcnt vmcnt(4)" ::: "memory");
  SBAR();
  BARRIER();

  for (int kt = 0; kt < 16; ++kt) {
    const int p = kt & 1;
    const int pb = p * 32768, qb = 32768 - pb;
    const int k1 = ((kt + 1) & 15) * 64;
    const int k2 = ((kt + 2) & 15) * 64;   // wrapped tail: junk reload, never read
    // phase A: all 24 ds_reads (pinned groups); stage (kt+1).Bh0
#pragma unroll
    for (int m = 0; m < 4; ++m)
#pragma unroll
      for (int ks = 0; ks < 2; ++ks) Af[m][ks] = rdA(pb, m, ks);
#pragma unroll
    for (int n = 0; n < 2; ++n)
#pragma unroll
      for (int ks = 0; ks < 2; ++ks) Bf[n][ks] = rdB(pb, n, ks);
    SBAR();                                         // pin group 1 (12 reads)
#pragma unroll
    for (int m = 0; m < 4; ++m)
#pragma unroll
      for (int ks = 0; ks < 2; ++ks) Af[4 + m][ks] = rdA(pb, 4 + m, ks);
    SBAR();                                         // pin group 2 (8 reads)
#pragma unroll
    for (int n = 2; n < 4; ++n)
#pragma unroll
      for (int ks = 0; ks < 2; ++ks) Bf[n][ks] = rdB(pb, n, ks);
    SBAR();                                         // pin group 3 (4 reads)
    stage_half(W, qb + 16384, brow0, k1);
    BARRIER();
    asm volatile("s_waitcnt lgkmcnt(12)" ::: "memory");  // group 1 done
    SBAR();
    quad(0, 0);
    BARRIER();
    // phase B: stage (kt+1).Bh1
    stage_half(W, qb + 16384 + 8192, brow0 + 128, k1);
    BARRIER();
    asm volatile("s_waitcnt lgkmcnt(4)" ::: "memory");   // + group 2 done
    SBAR();
    quad(4, 0);
    BARRIER();
    // phase C: stage (kt+2).Ah0 into freed rows 0-127 of buf p
    stage_half(A, pb, arow0, k2);
    BARRIER();
    asm volatile("s_waitcnt lgkmcnt(0)" ::: "memory");   // last 4 done
    SBAR();
    quad(0, 2);
    BARRIER();
    // phase D: stage (kt+2).Ah1; counted vmcnt
    stage_half(A, pb + 8192, arow0 + 128, k2);
    BARRIER();
    quad(4, 2);
    asm volatile("s_waitcnt vmcnt(4)" ::: "memory");     // kt+1 fully landed
    SBAR();
    BARRIER();
  }

  // epilogue: C/D layout col = lane&15, row = (lane>>4)*4 + j  [m89/m91]
#pragma unroll
  for (int n = 0; n < 4; ++n) {
    const int col = nt * 256 + wc * 64 + n * 16 + l15;
    const float bv2 = bias[col];
#pragma unroll
    for (int m = 0; m < 8; ++m) {
      const int row0 = mt * 256 + wr * 128 + m * 16 + lh * 4;
      if (outMode == 2) {
        const int b = row0 >> 13, tl = row0 & 8191;
        const int h = col >> 6, d = col & 63;
        s16x4_t o;
#pragma unroll
        for (int j = 0; j < 4; ++j) {
          float v = acc[m][n][j] + bv2;
          if (fmap) v = (v > 0.0f) ? (v + 1.0f) : __expf(v);
          o[j] = (short)f2bf_bits(v);
        }
        *reinterpret_cast<s16x4_t*>(Cout + (((b * 16 + h) * 64 + d) * 8192 + tl)) = o;
      } else {
#pragma unroll
        for (int j = 0; j < 4; ++j) {
          float v = acc[m][n][j] + bv2;
          if (fmap) v = (v > 0.0f) ? (v + 1.0f) : __expf(v);  // elu(x)+1
          Cout[(row0 + j) * NDIM + col] = f2bf_bits(v);
        }
      }
    }
  }
}

// ---------------------------------------------------------------- final GEMM (R9 verbatim)
__global__ __launch_bounds__(512, 2) void gemm_out(
    const unsigned short* __restrict__ A, const unsigned short* __restrict__ W,
    const float* __restrict__ bias, float* __restrict__ Cout) {
  __shared__ short lds[65536];
  const int bid = blockIdx.x;                     // 512 blocks
  const int swz = (bid & 7) * 64 + (bid >> 3);
  const int mt = swz >> 2;
  const int nt = swz & 3;

  const int tid = threadIdx.x;
  const int lane = tid & 63;
  const int w = tid >> 6;
  const int wr = w >> 2, wc = w & 3;
  const int l15 = lane & 15, lh = lane >> 4;

  const int arow0 = mt * 256, brow0 = nt * 256;

  auto stage_half = [&](const unsigned short* __restrict__ src, int ldsOff,
                        int grow, int k0) {
#pragma unroll
    for (int i = 0; i < 2; ++i) {
      const int c = i * 512 + tid;
      const int r = c >> 3, ps = c & 7;
      load_lds16(src + (grow + r) * KDIM + k0 + ((ps ^ (r & 7)) * 8),
                 &lds[ldsOff + c * 8]);
    }
  };

  f32x4_t acc[8][4];
#pragma unroll
  for (int m = 0; m < 8; ++m)
#pragma unroll
    for (int n = 0; n < 4; ++n) acc[m][n] = (f32x4_t)0.0f;

  s16x8_t Af[8][2], Bf[4][2];

  auto rdA = [&](int pb, int m, int ks) -> s16x8_t {
    const int row = wr * 128 + m * 16 + l15;
    return *reinterpret_cast<const s16x8_t*>(
        &lds[pb + row * 64 + (((ks * 4 + lh) ^ (row & 7)) * 8)]);
  };
  auto rdB = [&](int pb, int n, int ks) -> s16x8_t {
    const int row = wc * 64 + n * 16 + l15;
    return *reinterpret_cast<const s16x8_t*>(
        &lds[pb + 16384 + row * 64 + (((ks * 4 + lh) ^ (row & 7)) * 8)]);
  };
  auto quad = [&](int mb, int nl) {
    __builtin_amdgcn_s_setprio(1);
#pragma unroll
    for (int m = 0; m < 4; ++m)
#pragma unroll
      for (int n = 0; n < 2; ++n)
#pragma unroll
        for (int ks = 0; ks < 2; ++ks)
          acc[mb + m][nl + n] = __builtin_amdgcn_mfma_f32_16x16x32_bf16(
              __builtin_bit_cast(bf16x8_t, Af[mb + m][ks]),
              __builtin_bit_cast(bf16x8_t, Bf[nl + n][ks]),
              acc[mb + m][nl + n], 0, 0, 0);
    __builtin_amdgcn_s_setprio(0);
  };

  stage_half(A, 0,             arow0,       0);
  stage_half(A, 8192,          arow0 + 128, 0);
  stage_half(W, 16384,         brow0,       0);
  stage_half(W, 16384 + 8192,  brow0 + 128, 0);
  stage_half(A, 32768,         arow0,       64);
  stage_half(A, 32768 + 8192,  arow0 + 128, 64);
  asm volatile("s_waitcnt vmcnt(4)" ::: "memory");
  SBAR();
  BARRIER();

  for (int kt = 0; kt < 16; ++kt) {
    const int p = kt & 1;
    const int pb = p * 32768, qb = 32768 - pb;
    const int k1 = ((kt + 1) & 15) * 64;
    const int k2 = ((kt + 2) & 15) * 64;
#pragma unroll
    for (int m = 0; m < 4; ++m)
#pragma unroll
      for (int ks = 0; ks < 2; ++ks) Af[m][ks] = rdA(pb, m, ks);
#pragma unroll
    for (int n = 0; n < 2; ++n)
#pragma unroll
      for (int ks = 0; ks < 2; ++ks) Bf[n][ks] = rdB(pb, n, ks);
    SBAR();
#pragma unroll
    for (int m = 0; m < 4; ++m)
#pragma unroll
      for (int ks = 0; ks < 2; ++ks) Af[4 + m][ks] = rdA(pb, 4 + m, ks);
    SBAR();
#pragma unroll
    for (int n = 2; n < 4; ++n)
#pragma unroll
      for (int ks = 0; ks < 2; ++ks) Bf[n][ks] = rdB(pb, n, ks);
    SBAR();
    stage_half(W, qb + 16384, brow0, k1);
    BARRIER();
    asm volatile("s_waitcnt lgkmcnt(12)" ::: "memory");
    SBAR();
    quad(0, 0);
    BARRIER();
    stage_half(W, qb + 16384 + 8192, brow0 + 128, k1);
    BARRIER();
    asm volatile("s_waitcnt lgkmcnt(4)" ::: "memory");
    SBAR();
    quad(4, 0);
    BARRIER();
    stage_half(A, pb, arow0, k2);
    BARRIER();
    asm volatile("s_waitcnt lgkmcnt(0)" ::: "memory");
    SBAR();
    quad(0, 2);
    BARRIER();
    stage_half(A, pb + 8192, arow0 + 128, k2);
    BARRIER();
    quad(4, 2);
    asm volatile("s_waitcnt vmcnt(4)" ::: "memory");
    SBAR();
    BARRIER();
  }

#pragma unroll
  for (int n = 0; n < 4; ++n) {
    const int col = nt * 256 + wc * 64 + n * 16 + l15;
    const float bv = bias[col];
#pragma unroll
    for (int m = 0; m < 8; ++m) {
      const int row0 = mt * 256 + wr * 128 + m * 16 + lh * 4;
#pragma unroll
      for (int j = 0; j < 4; ++j)
        __builtin_nontemporal_store(acc[m][n][j] + bv,   // final f32: never re-read
                                    &Cout[(row0 + j) * NDIM + col]);
    }
  }
}

// ---------------------------------------------------------------- kv + k_sum (MFMA, streaming)
__global__ __launch_bounds__(256) void kv_ksum_mfma(
    const unsigned short* __restrict__ kT, const unsigned short* __restrict__ vT,
    float* __restrict__ kvT, float* __restrict__ ksum) {
  const int bid = blockIdx.x;
  const int bh = bid >> 4, ch = bid & 15;
  const int tid = threadIdx.x;
  const int lane = tid & 63, w = tid >> 6;
  const int l15 = lane & 15, lh = lane >> 4;
  const int dblk = (w >> 1) * 32, eblk = (w & 1) * 32;

  f32x4_t acc[2][2];
#pragma unroll
  for (int m = 0; m < 2; ++m)
#pragma unroll
    for (int n = 0; n < 2; ++n) acc[m][n] = (f32x4_t)0.0f;
  float ks0 = 0.f, ks1 = 0.f;

  const int tbase = ch * 512 + lh * 8;
  const unsigned short* ka = kT + (bh * 64 + dblk + l15) * 8192 + tbase;
  const unsigned short* va = vT + (bh * 64 + eblk + l15) * 8192 + tbase;

  for (int t0 = 0; t0 < 512; t0 += 32) {
    s16x8_t ar[2], br[2];
#pragma unroll
    for (int m = 0; m < 2; ++m)
      ar[m] = *reinterpret_cast<const s16x8_t*>(ka + m * 16 * 8192 + t0);
#pragma unroll
    for (int n = 0; n < 2; ++n)
      br[n] = *reinterpret_cast<const s16x8_t*>(va + n * 16 * 8192 + t0);
#pragma unroll
    for (int m = 0; m < 2; ++m)
#pragma unroll
      for (int n = 0; n < 2; ++n)
        acc[m][n] = __builtin_amdgcn_mfma_f32_16x16x32_bf16(
            __builtin_bit_cast(bf16x8_t, ar[m]),
            __builtin_bit_cast(bf16x8_t, br[n]), acc[m][n], 0, 0, 0);
    if (eblk == 0) {
#pragma unroll
      for (int i = 0; i < 8; ++i) ks0 += bf2f((unsigned short)ar[0][i]);
#pragma unroll
      for (int i = 0; i < 8; ++i) ks1 += bf2f((unsigned short)ar[1][i]);
    }
  }

  if (eblk == 0) {
    ks0 += __shfl_xor(ks0, 16); ks0 += __shfl_xor(ks0, 32);
    ks1 += __shfl_xor(ks1, 16); ks1 += __shfl_xor(ks1, 32);
    if (lh == 0) {
      atomicAdd(&ksum[bh * 64 + dblk + l15], ks0);
      atomicAdd(&ksum[bh * 64 + dblk + 16 + l15], ks1);
    }
  }
#pragma unroll
  for (int n = 0; n < 2; ++n) {
    const int e = eblk + n * 16 + l15;
#pragma unroll
    for (int m = 0; m < 2; ++m) {
      const int d0 = dblk + m * 16 + lh * 4;
#pragma unroll
      for (int j = 0; j < 4; ++j)
        atomicAdd(&kvT[(bh * 64 + e) * 64 + d0 + j], acc[m][n][j]);
    }
  }
}

// ---------------------------------------------------------------- out = q@kv / (q.ksum+eps)
__global__ __launch_bounds__(256) void attn_apply_kernel(
    const unsigned short* __restrict__ qf, const float* __restrict__ kvT,
    const float* __restrict__ ksum, unsigned short* __restrict__ att) {
  const int bid = blockIdx.x;                     // 2048
  const int swz = (bid & 7) * 256 + (bid >> 3);
  const int bh = swz >> 5;
  const int tile = swz & 31;
  const int b = bh >> 4, h = bh & 15;
  const int tid = threadIdx.x;
  const int lane = tid & 63, w = tid >> 6;
  const int l15 = lane & 15, lh = lane >> 4;

  float ksr[16];
#pragma unroll
  for (int i = 0; i < 16; ++i) ksr[i] = ksum[bh * 64 + lh * 16 + i];

  bf16x8_t bfrag[2][4];
#pragma unroll
  for (int ks2 = 0; ks2 < 2; ++ks2)
#pragma unroll
    for (int n = 0; n < 4; ++n) {
      const float* p = kvT + (bh * 64 + n * 16 + l15) * 64 + ks2 * 32 + lh * 8;
      f32x4_t p0 = *reinterpret_cast<const f32x4_t*>(p);
      f32x4_t p1 = *reinterpret_cast<const f32x4_t*>(p + 4);
      s16x8_t t;
      t[0] = (short)f2bf_bits(p0[0]); t[1] = (short)f2bf_bits(p0[1]);
      t[2] = (short)f2bf_bits(p0[2]); t[3] = (short)f2bf_bits(p0[3]);
      t[4] = (short)f2bf_bits(p1[0]); t[5] = (short)f2bf_bits(p1[1]);
      t[6] = (short)f2bf_bits(p1[2]); t[7] = (short)f2bf_bits(p1[3]);
      bfrag[ks2][n] = __builtin_bit_cast(bf16x8_t, t);
    }

  const int rbase = b * 8192 + tile * 256 + w * 64;
  f32x4_t acc[4][4];
#pragma unroll
  for (int m = 0; m < 4; ++m)
#pragma unroll
    for (int n = 0; n < 4; ++n) acc[m][n] = (f32x4_t)0.0f;
  float rden[4][4];

#pragma unroll
  for (int m = 0; m < 4; ++m) {
    const int row = rbase + m * 16 + l15;
    const unsigned short* qrow = qf + row * 1024 + h * 64;
    bf16x8_t afr[2];
#pragma unroll
    for (int ks2 = 0; ks2 < 2; ++ks2)
      afr[ks2] = __builtin_bit_cast(bf16x8_t,
          *reinterpret_cast<const s16x8_t*>(qrow + ks2 * 32 + lh * 8));
    s16x8_t qa = *reinterpret_cast<const s16x8_t*>(qrow + lh * 16);
    s16x8_t qb = *reinterpret_cast<const s16x8_t*>(qrow + lh * 16 + 8);
    float part = 0.f;
#pragma unroll
    for (int i = 0; i < 8; ++i) part += bf2f((unsigned short)qa[i]) * ksr[i];
#pragma unroll
    for (int i = 0; i < 8; ++i) part += bf2f((unsigned short)qb[i]) * ksr[8 + i];
    part += __shfl_xor(part, 16);
    part += __shfl_xor(part, 32);
#pragma unroll
    for (int j = 0; j < 4; ++j) {
      float dj = __shfl(part, lh * 4 + j);
      rden[m][j] = 1.0f / (dj + EPSV);
    }
#pragma unroll
    for (int ks2 = 0; ks2 < 2; ++ks2)
#pragma unroll
      for (int n = 0; n < 4; ++n)
        acc[m][n] = __builtin_amdgcn_mfma_f32_16x16x32_bf16(afr[ks2], bfrag[ks2][n], acc[m][n], 0, 0, 0);
  }

#pragma unroll
  for (int m = 0; m < 4; ++m)
#pragma unroll
    for (int n = 0; n < 4; ++n) {
      const int col = h * 64 + n * 16 + l15;
#pragma unroll
      for (int j = 0; j < 4; ++j) {
        const int row = rbase + m * 16 + lh * 4 + j;
        att[row * 1024 + col] = f2bf_bits(acc[m][n][j] * rden[m][j]);
      }
    }
}

// ---------------------------------------------------------------- launch
extern "C" void kernel_launch(void* const* d_in, const int* in_sizes, int n_in,
                              void* d_out, int out_size, void* d_ws, size_t ws_size,
                              hipStream_t stream) {
  const float* query = (const float*)d_in[0];
  const float* key   = (const float*)d_in[1];
  const float* value = (const float*)d_in[2];
  const float* Wq = (const float*)d_in[3];
  const float* bq = (const float*)d_in[4];
  const float* Wk = (const float*)d_in[5];
  const float* bk = (const float*)d_in[6];
  const float* Wv = (const float*)d_in[7];
  const float* bv = (const float*)d_in[8];
  const float* Wo = (const float*)d_in[9];
  const float* bo = (const float*)d_in[10];
  float* out = (float*)d_out;

  if (ws_size < 277889024ULL) return;
  char* ws = (char*)d_ws;
  unsigned short* Vbf = (unsigned short*)(ws + 0);          // value bf16; reused as att
  unsigned short* qf  = (unsigned short*)(ws + 67108864);
  unsigned short* kTf = (unsigned short*)(ws + 134217728);  // k transposed [b][h][d][t]
  unsigned short* vTf = (unsigned short*)(ws + 201326592);  // v transposed
  unsigned short* Wqb = (unsigned short*)(ws + 268435456);
  unsigned short* Wkb = Wqb + 1048576;
  unsigned short* Wvb = Wkb + 1048576;
  unsigned short* Wob = Wvb + 1048576;
  float* kvT  = (float*)(ws + 276824064);
  float* ksum = (float*)(ws + 277872640);

  unsigned short* Qbf = (unsigned short*)d_out;   // d_out doubles as bf16 scratch
  unsigned short* Kbf = Qbf + 33554432;

  hipMemsetAsync(kvT, 0, (size_t)(64 * 64 * 64 + 64 * 64) * sizeof(float), stream);

  convert_all_f32_bf16<<<8192, 256, 0, stream>>>(
      query, key, value, Wq, Wk, Wv, Wo,
      Qbf, Kbf, Vbf, Wqb, Wkb, Wvb, Wob);

  gemm_qkv<<<1536, 512, 0, stream>>>(Qbf, Kbf, Vbf, Wqb, Wkb, Wvb,
                                     bq, bk, bv, qf, kTf, vTf);

  kv_ksum_mfma<<<1024, 256, 0, stream>>>(kTf, vTf, kvT, ksum);

  attn_apply_kernel<<<2048, 256, 0, stream>>>(qf, kvT, ksum, Vbf);  // att -> Vbf

  gemm_out<<<512, 512, 0, stream>>>(Vbf, Wob, bo, out);  // final -> f32
}